// Round 4
// baseline (24.889 us; speedup 1.0000x reference)
//
#include <hip/hip_runtime.h>

// AffinityFeature, symmetric formulation + 2D tiling for intra-block row reuse.
// out[b][a][h][w] = relu( cos(feat[b,:,h,w], feat[b,:,h+dh,w+dw]) ), 0 if OOB.
// a order: 0:NW 1:N 2:NE 3:W 4:E 5:SW 6:S 7:SE.
// Symmetry: dot(p,q)=dot(q,p) -> compute only E,S,SE,SW per pixel, scatter
// the mirrored channels (W,N,NW,NE) to the neighbor pixel's location.
// Block = 8 rows x 128 cols tile (256 threads x 4 px); rows h0+1..h0+7 are
// read as center AND south within the same block -> L1/L2 absorbs the re-read.

#define AF_B 4
#define AF_C 32
#define AF_H 256
#define AF_W 512
#define AF_EPS 1e-12f
#define AF_PLANE ((size_t)AF_H * AF_W)

__global__ __launch_bounds__(256) void affinity_sym_kernel(const float* __restrict__ f,
                                                           float* __restrict__ out) {
    // XCD-aware swizzle: 512 blocks, 8 XCDs -> 64-block contiguous band/XCD
    // (a 128-row slab of one batch: 16 h-bands x 4 w-bands).
    const int cpx = gridDim.x >> 3;
    const int bid = ((int)blockIdx.x & 7) * cpx + ((int)blockIdx.x >> 3);

    // bid -> (b, hband, wband); wband innermost for w-halo L2 sharing
    const int wband = bid & 3;
    const int hband = (bid >> 2) & 31;
    const int b = bid >> 7;

    const int g = (int)threadIdx.x & 31;       // col group in tile
    const int r = (int)threadIdx.x >> 5;       // row in tile (0..7)
    const int w0 = (wband << 7) + (g << 2);    // 0..508
    const int h = (hband << 3) + r;            // 0..255

    const bool vS = (h + 1) < AF_H;   // south row exists
    const bool vR = (w0 + 4) < AF_W;  // col w0+4 exists
    const bool vL = w0 > 0;           // col w0-1 exists
    const float mS = vS ? 1.0f : 0.0f;
    const float mR = vR ? 1.0f : 0.0f;
    const float mRS = mR * mS;
    const float mLS = (vL ? 1.0f : 0.0f) * mS;
    const int offR = vR ? 4 : 0;
    const int offL = vL ? -1 : 0;

    const float* pc = f + (size_t)b * AF_C * AF_PLANE + (size_t)h * AF_W + w0;
    const float* ps = pc + (vS ? AF_W : 0);

    float ssq0=0,ssq1=0,ssq2=0,ssq3=0, ssqR=0;          // center row |v|^2
    float nsq0=0,nsq1=0,nsq2=0,nsq3=0, nsqL=0,nsqR=0;   // south row |v|^2
    float dE0=0,dE1=0,dE2=0,dE3=0;
    float dS0=0,dS1=0,dS2=0,dS3=0;
    float dSE0=0,dSE1=0,dSE2=0,dSE3=0;
    float dSW0=0,dSW1=0,dSW2=0,dSW3=0;

#pragma unroll
    for (int c = 0; c < AF_C; ++c) {
        const float4 cc = *(const float4*)pc;
        const float ccR = pc[offR] * mR;
        float4 cs = *(const float4*)ps;
        const float csR = ps[offR] * mRS;
        const float csL = ps[offL] * mLS;
        cs.x *= mS; cs.y *= mS; cs.z *= mS; cs.w *= mS;
        pc += AF_PLANE; ps += AF_PLANE;

        ssq0 += cc.x*cc.x; ssq1 += cc.y*cc.y; ssq2 += cc.z*cc.z; ssq3 += cc.w*cc.w;
        ssqR += ccR*ccR;
        nsq0 += cs.x*cs.x; nsq1 += cs.y*cs.y; nsq2 += cs.z*cs.z; nsq3 += cs.w*cs.w;
        nsqL += csL*csL;   nsqR += csR*csR;
        dE0 += cc.x*cc.y;  dE1 += cc.y*cc.z;  dE2 += cc.z*cc.w;  dE3 += cc.w*ccR;
        dS0 += cc.x*cs.x;  dS1 += cc.y*cs.y;  dS2 += cc.z*cs.z;  dS3 += cc.w*cs.w;
        dSE0 += cc.x*cs.y; dSE1 += cc.y*cs.z; dSE2 += cc.z*cs.w; dSE3 += cc.w*csR;
        dSW0 += cc.x*csL;  dSW1 += cc.y*cs.x; dSW2 += cc.z*cs.y; dSW3 += cc.w*cs.z;
    }

    const float ic0 = 1.0f / fmaxf(sqrtf(ssq0), AF_EPS);
    const float ic1 = 1.0f / fmaxf(sqrtf(ssq1), AF_EPS);
    const float ic2 = 1.0f / fmaxf(sqrtf(ssq2), AF_EPS);
    const float ic3 = 1.0f / fmaxf(sqrtf(ssq3), AF_EPS);
    const float icR = 1.0f / fmaxf(sqrtf(ssqR), AF_EPS);
    const float is0 = 1.0f / fmaxf(sqrtf(nsq0), AF_EPS);
    const float is1 = 1.0f / fmaxf(sqrtf(nsq1), AF_EPS);
    const float is2 = 1.0f / fmaxf(sqrtf(nsq2), AF_EPS);
    const float is3 = 1.0f / fmaxf(sqrtf(nsq3), AF_EPS);
    const float isL = 1.0f / fmaxf(sqrtf(nsqL), AF_EPS);
    const float isR = 1.0f / fmaxf(sqrtf(nsqR), AF_EPS);

    const float E0 = fmaxf(dE0*ic0*ic1, 0.0f);
    const float E1 = fmaxf(dE1*ic1*ic2, 0.0f);
    const float E2 = fmaxf(dE2*ic2*ic3, 0.0f);
    const float E3 = fmaxf(dE3*ic3*icR, 0.0f);
    const float S0 = fmaxf(dS0*ic0*is0, 0.0f);
    const float S1 = fmaxf(dS1*ic1*is1, 0.0f);
    const float S2 = fmaxf(dS2*ic2*is2, 0.0f);
    const float S3 = fmaxf(dS3*ic3*is3, 0.0f);
    const float SE0 = fmaxf(dSE0*ic0*is1, 0.0f);
    const float SE1 = fmaxf(dSE1*ic1*is2, 0.0f);
    const float SE2 = fmaxf(dSE2*ic2*is3, 0.0f);
    const float SE3 = fmaxf(dSE3*ic3*isR, 0.0f);
    const float SW0 = fmaxf(dSW0*ic0*isL, 0.0f);
    const float SW1 = fmaxf(dSW1*ic1*is0, 0.0f);
    const float SW2 = fmaxf(dSW2*ic2*is1, 0.0f);
    const float SW3 = fmaxf(dSW3*ic3*is2, 0.0f);

    float* ob = out + (size_t)b * 8 * AF_PLANE + (size_t)h * AF_W + w0;

    // forward channels at (h, w0..w0+3), aligned float4
    *(float4*)(ob + 4*AF_PLANE) = make_float4(E0,E1,E2,E3);
    *(float4*)(ob + 6*AF_PLANE) = make_float4(S0,S1,S2,S3);
    *(float4*)(ob + 7*AF_PLANE) = make_float4(SE0,SE1,SE2,SE3);
    *(float4*)(ob + 5*AF_PLANE) = make_float4(SW0,SW1,SW2,SW3);

    // a=3 (W) at (h, w0+1..w0+4)
    float* o3 = ob + 3*AF_PLANE;
    o3[1] = E0; o3[2] = E1; o3[3] = E2;
    if (vR) o3[4] = E3;
    if (!vL) o3[0] = 0.0f;      // W of (h,0) OOB

    if (vS) {
        float* on = ob + AF_W;  // row h+1, col w0
        // a=1 (N) at (h+1, w0..w0+3)
        *(float4*)(on + 1*AF_PLANE) = make_float4(S0,S1,S2,S3);
        // a=0 (NW) at (h+1, w0+1..w0+4)
        float* o0 = on;
        o0[1] = SE0; o0[2] = SE1; o0[3] = SE2;
        if (vR) o0[4] = SE3;
        if (!vL) o0[0] = 0.0f;  // NW of (h+1,0) OOB
        // a=2 (NE) at (h+1, w0-1..w0+2)
        float* o2 = on + 2*AF_PLANE;
        if (vL) o2[-1] = SW0;
        o2[0] = SW1; o2[1] = SW2; o2[2] = SW3;
        if (!vR) o2[3] = 0.0f;  // NE of (h+1, W-1) OOB
    }

    if (h == 0) {               // N/NW/NE rows at h=0 are all OOB -> zero
        float* oz = out + (size_t)b * 8 * AF_PLANE + w0;
        const float4 z4 = make_float4(0.0f, 0.0f, 0.0f, 0.0f);
        *(float4*)(oz + 0*AF_PLANE) = z4;
        *(float4*)(oz + 1*AF_PLANE) = z4;
        *(float4*)(oz + 2*AF_PLANE) = z4;
    }
}

extern "C" void kernel_launch(void* const* d_in, const int* in_sizes, int n_in,
                              void* d_out, int out_size, void* d_ws, size_t ws_size,
                              hipStream_t stream) {
    const float* f = (const float*)d_in[0];
    float* out = (float*)d_out;
    // grid = 4 batches x 32 h-bands x 4 w-bands = 512 blocks of 256 threads
    affinity_sym_kernel<<<512, 256, 0, stream>>>(f, out);
}

// Round 5
// 24.014 us; speedup vs baseline: 1.0364x; 1.0364x over previous
//
#include <hip/hip_runtime.h>

// AffinityFeature: out[b][a][h][w] = relu(cos(feat[b,:,h,w], feat[b,:,h+dh,w+dw])), 0 if OOB.
// a: 0:NW 1:N 2:NE 3:W 4:E 5:SW 6:S 7:SE. Symmetric: compute E,S,SE,SW per
// pixel, scatter mirrors (W,N,NW,NE) to the neighbor's location.
// Structure: 8x64-px block (256 thr, 2 px/thread -> 4096 waves = 4/SIMD),
// LDS-staged channel slices (9 rows x 72 cols, halo pre-zeroed), double-
// buffered: prefetch channel c+1 from global while computing c from LDS.

#define AF_B 4
#define AF_C 32
#define AF_H 256
#define AF_W 512
#define AF_EPS 1e-12f
#define AF_PLANE ((size_t)AF_H * AF_W)

#define LROW 72     // staged floats per row: cols [w0-4, w0+68)
#define LROWS 9     // staged rows: h0 .. h0+8
#define NSLOT 162   // LROWS * LROW / 4 float4 slots

__global__ __launch_bounds__(256) void affinity_lds_kernel(const float* __restrict__ f,
                                                           float* __restrict__ out) {
    __shared__ float tile[2][LROWS][LROW];   // 5.2 KB

    // XCD-aware swizzle: 1024 blocks -> 128-block contiguous slab per XCD
    const int cpx = gridDim.x >> 3;
    const int bid = ((int)blockIdx.x & 7) * cpx + ((int)blockIdx.x >> 3);
    const int wband = bid & 7;            // 8 w-bands of 64 cols
    const int hband = (bid >> 3) & 31;    // 32 h-bands of 8 rows
    const int b = bid >> 8;               // 4 batches

    const int h0 = hband << 3;
    const int wb0 = wband << 6;
    const int tid = (int)threadIdx.x;

    // ---- staging descriptor (fixed per thread): slot -> (srow, scol4) ----
    const int slot = tid;
    const int srow = slot / 18;                    // 0..8 (18 float4 per row)
    const int scol4 = slot - srow * 18;            // 0..17
    const int gcol = wb0 + (scol4 << 2) - 4;       // global col of chunk
    const int grow = h0 + srow;                    // global row
    const bool sv = (slot < NSLOT) && (gcol >= 0) && (gcol < AF_W) && (grow < AF_H);
    const size_t goff = (size_t)(sv ? grow : 0) * AF_W + (sv ? gcol : 0);
    const float* gsrc = f + (size_t)b * AF_C * AF_PLANE + goff;
    float* lslot0 = &tile[0][0][0] + (slot << 2);  // linear float4 slots
    float* lslot1 = &tile[1][0][0] + (slot << 2);

    // pre-zero both buffers (halo slots stay 0 forever), stage channel 0
    if (slot < NSLOT) {
        *(float4*)lslot0 = make_float4(0.f, 0.f, 0.f, 0.f);
        *(float4*)lslot1 = make_float4(0.f, 0.f, 0.f, 0.f);
    }
    if (sv) *(float4*)lslot0 = *(const float4*)gsrc;
    __syncthreads();

    // ---- compute descriptor: 2 px/thread ----
    const int g = tid & 31;          // col-pair group
    const int r = tid >> 5;          // row in tile 0..7
    const int lcol = (g << 1) + 4;   // LDS col of w0
    const int h = h0 + r;
    const int w0 = wb0 + (g << 1);

    float ssq0=0, ssq1=0, ssqR=0;
    float nsq0=0, nsq1=0, nsqL=0, nsqR=0;
    float dE0=0, dE1=0, dS0=0, dS1=0, dSE0=0, dSE1=0, dSW0=0, dSW1=0;

    const float* gnext = gsrc;
#pragma unroll 4
    for (int c = 0; c < AF_C; ++c) {
        // issue next-channel stage load early; latency hides under compute
        float4 nx;
        const bool pf = sv && (c + 1 < AF_C);
        if (pf) { gnext += AF_PLANE; nx = *(const float4*)gnext; }

        const float (*cur)[LROW] = tile[c & 1];
        const float2 cc = *(const float2*)&cur[r][lcol];        // center w0,w0+1
        const float2 cs = *(const float2*)&cur[r + 1][lcol];    // south  w0,w0+1
        const float ccR = cur[r][lcol + 2];                     // center w0+2
        const float csR = cur[r + 1][lcol + 2];                 // south  w0+2
        const float csL = cur[r + 1][lcol - 1];                 // south  w0-1

        ssq0 += cc.x*cc.x; ssq1 += cc.y*cc.y; ssqR += ccR*ccR;
        nsq0 += cs.x*cs.x; nsq1 += cs.y*cs.y; nsqL += csL*csL; nsqR += csR*csR;
        dE0  += cc.x*cc.y; dE1  += cc.y*ccR;
        dS0  += cc.x*cs.x; dS1  += cc.y*cs.y;
        dSE0 += cc.x*cs.y; dSE1 += cc.y*csR;
        dSW0 += cc.x*csL;  dSW1 += cc.y*cs.x;

        // write prefetched channel into the other buffer, then sync
        if (pf) *(float4*)((c & 1) ? lslot0 : lslot1) = nx;
        __syncthreads();
    }

    const float ic0 = 1.0f / fmaxf(sqrtf(ssq0), AF_EPS);
    const float ic1 = 1.0f / fmaxf(sqrtf(ssq1), AF_EPS);
    const float icR = 1.0f / fmaxf(sqrtf(ssqR), AF_EPS);
    const float is0 = 1.0f / fmaxf(sqrtf(nsq0), AF_EPS);
    const float is1 = 1.0f / fmaxf(sqrtf(nsq1), AF_EPS);
    const float isL = 1.0f / fmaxf(sqrtf(nsqL), AF_EPS);
    const float isR = 1.0f / fmaxf(sqrtf(nsqR), AF_EPS);

    const float E0  = fmaxf(dE0 *ic0*ic1, 0.0f);
    const float E1  = fmaxf(dE1 *ic1*icR, 0.0f);
    const float S0  = fmaxf(dS0 *ic0*is0, 0.0f);
    const float S1  = fmaxf(dS1 *ic1*is1, 0.0f);
    const float SE0 = fmaxf(dSE0*ic0*is1, 0.0f);
    const float SE1 = fmaxf(dSE1*ic1*isR, 0.0f);
    const float SW0 = fmaxf(dSW0*ic0*isL, 0.0f);
    const float SW1 = fmaxf(dSW1*ic1*is0, 0.0f);

    float* obase = out + (size_t)b * 8 * AF_PLANE + (size_t)h * AF_W + w0;
    const bool vR2 = (w0 + 2) < AF_W;   // col w0+2 exists
    const bool vL  = w0 > 0;
    const bool vS  = (h + 1) < AF_H;

    // forward channels at (h, w0..w0+1)
    *(float2*)(obase + 4*AF_PLANE) = make_float2(E0, E1);
    *(float2*)(obase + 5*AF_PLANE) = make_float2(SW0, SW1);
    *(float2*)(obase + 6*AF_PLANE) = make_float2(S0, S1);
    *(float2*)(obase + 7*AF_PLANE) = make_float2(SE0, SE1);

    // a=3 (W): W(h,w) = E(h,w-1)
    float* p3 = obase + 3*AF_PLANE;
    p3[1] = E0;
    if (vR2) p3[2] = E1;
    if (!vL) p3[0] = 0.0f;              // W of col 0 OOB

    if (vS) {
        float* onb = obase + AF_W;      // row h+1
        *(float2*)(onb + 1*AF_PLANE) = make_float2(S0, S1);   // N
        float* p0 = onb;                // NW(h+1,w) = SE(h,w-1)
        p0[1] = SE0;
        if (vR2) p0[2] = SE1;
        if (!vL) p0[0] = 0.0f;
        float* p2 = onb + 2*AF_PLANE;   // NE(h+1,w) = SW(h,w+1)
        if (vL) p2[-1] = SW0;
        p2[0] = SW1;
        if (!vR2) p2[1] = 0.0f;         // NE of col W-1 OOB
    }

    if (h == 0) {                        // N/NW/NE at h=0 all OOB
        float* oz = out + (size_t)b * 8 * AF_PLANE + w0;
        const float2 z2 = make_float2(0.0f, 0.0f);
        *(float2*)(oz + 0*AF_PLANE) = z2;
        *(float2*)(oz + 1*AF_PLANE) = z2;
        *(float2*)(oz + 2*AF_PLANE) = z2;
    }
}

extern "C" void kernel_launch(void* const* d_in, const int* in_sizes, int n_in,
                              void* d_out, int out_size, void* d_ws, size_t ws_size,
                              hipStream_t stream) {
    const float* f = (const float*)d_in[0];
    float* out = (float*)d_out;
    // grid = 4 batches x 32 h-bands x 8 w-bands = 1024 blocks of 256 threads
    affinity_lds_kernel<<<1024, 256, 0, stream>>>(f, out);
}